// Round 6
// baseline (731.643 us; speedup 1.0000x reference)
//
#include <hip/hip_runtime.h>
#include <math.h>

#define CCH 48
#define NST 16
#define VOX (64*64*64)

__device__ __forceinline__ float softplus_f(float s) {
    return fmaxf(s, 0.f) + log1pf(__expf(-fabsf(s)));
}

template<int CTRL>
__device__ __forceinline__ float dpp_add(float x) {
    int v = __builtin_amdgcn_update_dpp(0, __float_as_int(x), CTRL, 0xF, 0xF, true);
    return x + __int_as_float(v);
}

// compile-time float4 component select (j must be a constant after unroll)
#define GETC(v, j) ((j) == 0 ? (v).x : ((j) == 1 ? (v).y : ((j) == 2 ? (v).z : (v).w)))

__global__ __launch_bounds__(256) void k_transpose_in(const float* __restrict__ x,
                                                      float* __restrict__ xt) {
    __shared__ float tile[CCH * 65];
    int v0 = blockIdx.x * 64;
    int t = threadIdx.x;
#pragma unroll
    for (int i = 0; i < 12; ++i) {
        int idx = t + i * 256;
        int c = idx >> 6, v = idx & 63;
        tile[c * 65 + v] = x[c * VOX + v0 + v];
    }
    __syncthreads();
#pragma unroll
    for (int i = 0; i < 12; ++i) {
        int idx = t + i * 256;
        int v = idx / CCH, c = idx - v * CCH;
        xt[(v0 + v) * CCH + c] = tile[c * 65 + v];
    }
}

__global__ __launch_bounds__(256) void k_transpose_out(const float* __restrict__ yws,
                                                       float* __restrict__ out) {
    __shared__ float tile[CCH * 65];
    int v0 = blockIdx.x * 64;
    int t = threadIdx.x;
#pragma unroll
    for (int i = 0; i < 12; ++i) {
        int idx = t + i * 256;
        int v = idx / CCH, c = idx - v * CCH;
        tile[c * 65 + v] = yws[(v0 + v) * CCH + c];
    }
    __syncthreads();
#pragma unroll
    for (int i = 0; i < 12; ++i) {
        int idx = t + i * 256;
        int c = idx >> 6, v = idx & 63;
        out[c * VOX + v0 + v] = tile[c * 65 + v];
    }
}

// LDS layout (float offsets) — unchanged from round 5.
#define OFF_XS    0        // 3072  xs[l*48+c]
#define OFF_WDT   3072     // 2496  wdtT[c*52+k]
#define OFF_WB    5568     // 832   wBT[n*52+k]
#define OFF_WC    6400     // 832   wCT[n*52+k]
#define OFF_DTS   7232     // 3264  dtsT[c*68+l]
#define OFF_UX    10496    // 3264  uxT[c*68+l]
#define OFF_BC    13760    // 1088  BcsT[n*68+l]
#define OFF_CC    14848    // 1088  CcsT[n*68+l]
#define OFF_YS    3072     // 3072  ys[l*48+c]  (aliases weights after projections)
#define SMEM_FLOATS 15936  // 63,744 B -> 2 blocks/CU

__global__ __launch_bounds__(768, 6) void k_scan(
    const float* __restrict__ xt, float* __restrict__ yws,
    const float* __restrict__ A_log, const float* __restrict__ W_dt,
    const float* __restrict__ b_dt, const float* __restrict__ W_B,
    const float* __restrict__ W_C, const float* __restrict__ D_skip,
    int dir, int stride_v, int accumulate)
{
    __shared__ __align__(16) float smem[SMEM_FLOATS];
    float* xs   = smem + OFF_XS;
    float* wdtT = smem + OFF_WDT;
    float* wBT  = smem + OFF_WB;
    float* wCT  = smem + OFF_WC;
    float* dtsT = smem + OFF_DTS;
    float* uxT  = smem + OFF_UX;
    float* BcsT = smem + OFF_BC;
    float* CcsT = smem + OFF_CC;
    float* ys   = smem + OFF_YS;

    int t = threadIdx.x;
    int lid = blockIdx.x;
    int a = lid >> 6, b = lid & 63;
    int vbase;
    if (dir == 0) vbase = lid;                 // step stride 4096 (along D)
    else if (dir == 1) vbase = a * 4096 + b;   // step stride 64   (along H)
    else vbase = a * 4096 + b * 64;            // step stride 1    (along W)

    const float* wdt_g = W_dt + dir * CCH * CCH;
    const float* wB_g  = W_B + dir * CCH * NST;
    const float* wC_g  = W_C + dir * CCH * NST;

    // ---- stage line of x (one float4 per thread) ----
    {
        int q = t % 12, l = t / 12;
        *(float4*)&xs[l * CCH + 4 * q] =
            *(const float4*)&xt[(vbase + l * stride_v) * CCH + 4 * q];
    }
    // ---- stage transposed weights ----
    for (int idx = t; idx < CCH * CCH; idx += 768) {
        int k = idx / CCH, c2 = idx - k * CCH;
        wdtT[c2 * 52 + k] = wdt_g[idx];
    }
    {
        int k = t >> 4, n2 = t & 15;
        wBT[n2 * 52 + k] = wB_g[t];
        wCT[n2 * 52 + k] = wC_g[t];
    }
    __syncthreads();

    // ---- fused register-tiled projections: 320 threads, 4 rows x 4 l each ----
    // Output rows: og 0..11 -> dt channels (4 each); og 12..15 -> B rows; 16..19 -> C rows.
    // k-index rotation qq=(q+lq)%12 staggers the l-quad reads across banks
    // (without it, lq stride = 192 words ≡ 0 mod 32 -> 16-way conflict).
    if (t < 320) {
        int lq = t & 15;          // l-quad: l = 4*lq + i
        int og = t >> 4;          // output row group
        int lqm = lq - ((lq >= 12) ? 12 : 0);   // lq % 12
        const float* wArr;
        float* dst;
        int r0;
        bool isDt = (og < 12);
        if (isDt) { r0 = og * 4; wArr = wdtT; dst = dtsT; }
        else {
            int r = (og - 12) * 4;
            if (r < 16) { wArr = wBT;  dst = BcsT; r0 = r; }
            else        { wArr = wCT;  dst = CcsT; r0 = r - 16; }
        }
        float acc[4][4] = {{0.f,0.f,0.f,0.f},{0.f,0.f,0.f,0.f},
                           {0.f,0.f,0.f,0.f},{0.f,0.f,0.f,0.f}};
#pragma unroll
        for (int q = 0; q < 12; ++q) {
            int qq = q + lqm; if (qq >= 12) qq -= 12;
            float4 wv[4], xv[4];
#pragma unroll
            for (int j = 0; j < 4; ++j)
                wv[j] = *(const float4*)&wArr[(r0 + j) * 52 + 4 * qq];
#pragma unroll
            for (int i = 0; i < 4; ++i)
                xv[i] = *(const float4*)&xs[(4 * lq + i) * CCH + 4 * qq];
#pragma unroll
            for (int j = 0; j < 4; ++j) {
#pragma unroll
                for (int i = 0; i < 4; ++i) {
                    acc[j][i] = fmaf(wv[j].x, xv[i].x, acc[j][i]);
                    acc[j][i] = fmaf(wv[j].y, xv[i].y, acc[j][i]);
                    acc[j][i] = fmaf(wv[j].z, xv[i].z, acc[j][i]);
                    acc[j][i] = fmaf(wv[j].w, xv[i].w, acc[j][i]);
                }
            }
        }
        if (isDt) {
            float4 xq[4];
#pragma unroll
            for (int i = 0; i < 4; ++i)
                xq[i] = *(const float4*)&xs[(4 * lq + i) * CCH + r0];
#pragma unroll
            for (int j = 0; j < 4; ++j) {
                float bias = b_dt[dir * CCH + r0 + j];
                float4 dtv, uxv;
                dtv.x = softplus_f(acc[j][0] + bias);
                dtv.y = softplus_f(acc[j][1] + bias);
                dtv.z = softplus_f(acc[j][2] + bias);
                dtv.w = softplus_f(acc[j][3] + bias);
                uxv.x = dtv.x * GETC(xq[0], j);
                uxv.y = dtv.y * GETC(xq[1], j);
                uxv.z = dtv.z * GETC(xq[2], j);
                uxv.w = dtv.w * GETC(xq[3], j);
                *(float4*)&dtsT[(r0 + j) * 68 + 4 * lq] = dtv;
                *(float4*)&uxT[(r0 + j) * 68 + 4 * lq]  = uxv;
            }
        } else {
#pragma unroll
            for (int j = 0; j < 4; ++j) {
                float4 o4;
                o4.x = acc[j][0]; o4.y = acc[j][1];
                o4.z = acc[j][2]; o4.w = acc[j][3];
                *(float4*)&dst[(r0 + j) * 68 + 4 * lq] = o4;
            }
        }
    }
    __syncthreads();

    // ---- sequential scan: thread owns state (c,n) ----
    {
        int cc = t >> 4, n = t & 15;
        float a_cn = -expf(A_log[dir * CCH * NST + cc * NST + n]);
        const float4* dt4 = (const float4*)&dtsT[cc * 68];
        const float4* ux4 = (const float4*)&uxT[cc * 68];
        const float4* B4  = (const float4*)&BcsT[n * 68];
        const float4* C4  = (const float4*)&CcsT[n * 68];
        float h = 0.f;

#define STEP(COMP, LIDX)                                                    \
        h = fmaf(__expf(dtv.COMP * a_cn), h, uxv.COMP * Bv.COMP);           \
        {                                                                   \
            float p = h * Cv.COMP;                                          \
            p = dpp_add<0x121>(p);                                          \
            p = dpp_add<0x122>(p);                                          \
            p = dpp_add<0x124>(p);                                          \
            p = dpp_add<0x128>(p);                                          \
            if (n == 0) ys[(LIDX) * CCH + cc] = p;                          \
        }

#pragma unroll
        for (int l4 = 0; l4 < 16; ++l4) {
            float4 dtv = dt4[l4];
            float4 uxv = ux4[l4];
            float4 Bv  = B4[l4];
            float4 Cv  = C4[l4];
            STEP(x, l4 * 4 + 0)
            STEP(y, l4 * 4 + 1)
            STEP(z, l4 * 4 + 2)
            STEP(w, l4 * 4 + 3)
        }
#undef STEP
    }
    __syncthreads();

    // ---- add skip term and write/accumulate to yws ----
    {
        int q = t % 12, l = t / 12;
        float4 yv = *(const float4*)&ys[l * CCH + 4 * q];
        float4 xv = *(const float4*)&xs[l * CCH + 4 * q];
        float4 dv = *(const float4*)&D_skip[dir * CCH + 4 * q];
        yv.x = fmaf(dv.x, xv.x, yv.x);
        yv.y = fmaf(dv.y, xv.y, yv.y);
        yv.z = fmaf(dv.z, xv.z, yv.z);
        yv.w = fmaf(dv.w, xv.w, yv.w);
        float* gp = &yws[(vbase + l * stride_v) * CCH + 4 * q];
        if (accumulate) {
            float4 old = *(const float4*)gp;
            yv.x += old.x; yv.y += old.y; yv.z += old.z; yv.w += old.w;
        }
        *(float4*)gp = yv;
    }
}

extern "C" void kernel_launch(void* const* d_in, const int* in_sizes, int n_in,
                              void* d_out, int out_size, void* d_ws, size_t ws_size,
                              hipStream_t stream) {
    const float* x      = (const float*)d_in[0];
    const float* A_log  = (const float*)d_in[1];
    const float* W_dt   = (const float*)d_in[2];
    const float* b_dt   = (const float*)d_in[3];
    const float* W_B    = (const float*)d_in[4];
    const float* W_C    = (const float*)d_in[5];
    const float* D_skip = (const float*)d_in[6];
    float* out = (float*)d_out;

    float* xt  = (float*)d_ws;
    float* yws = xt + (size_t)VOX * CCH;

    k_transpose_in<<<VOX / 64, 256, 0, stream>>>(x, xt);
    k_scan<<<4096, 768, 0, stream>>>(xt, yws, A_log, W_dt, b_dt, W_B, W_C, D_skip, 0, 4096, 0);
    k_scan<<<4096, 768, 0, stream>>>(xt, yws, A_log, W_dt, b_dt, W_B, W_C, D_skip, 1, 64, 1);
    k_scan<<<4096, 768, 0, stream>>>(xt, yws, A_log, W_dt, b_dt, W_B, W_C, D_skip, 2, 1, 1);
    k_transpose_out<<<VOX / 64, 256, 0, stream>>>(yws, out);
}

// Round 7
// 686.482 us; speedup vs baseline: 1.0658x; 1.0658x over previous
//
#include <hip/hip_runtime.h>
#include <math.h>

#define CCH 48
#define NST 16
#define VOX (64*64*64)

__device__ __forceinline__ float softplus_f(float s) {
    return fmaxf(s, 0.f) + log1pf(__expf(-fabsf(s)));
}

template<int CTRL>
__device__ __forceinline__ float dpp_add(float x) {
    int v = __builtin_amdgcn_update_dpp(0, __float_as_int(x), CTRL, 0xF, 0xF, true);
    return x + __int_as_float(v);
}

__global__ __launch_bounds__(256) void k_transpose_in(const float* __restrict__ x,
                                                      float* __restrict__ xt) {
    __shared__ float tile[CCH * 65];
    int v0 = blockIdx.x * 64;
    int t = threadIdx.x;
#pragma unroll
    for (int i = 0; i < 12; ++i) {
        int idx = t + i * 256;
        int c = idx >> 6, v = idx & 63;
        tile[c * 65 + v] = x[c * VOX + v0 + v];
    }
    __syncthreads();
#pragma unroll
    for (int i = 0; i < 12; ++i) {
        int idx = t + i * 256;
        int v = idx / CCH, c = idx - v * CCH;
        xt[(v0 + v) * CCH + c] = tile[c * 65 + v];
    }
}

__global__ __launch_bounds__(256) void k_transpose_out(const float* __restrict__ yws,
                                                       float* __restrict__ out) {
    __shared__ float tile[CCH * 65];
    int v0 = blockIdx.x * 64;
    int t = threadIdx.x;
#pragma unroll
    for (int i = 0; i < 12; ++i) {
        int idx = t + i * 256;
        int v = idx / CCH, c = idx - v * CCH;
        tile[c * 65 + v] = yws[(v0 + v) * CCH + c];
    }
    __syncthreads();
#pragma unroll
    for (int i = 0; i < 12; ++i) {
        int idx = t + i * 256;
        int c = idx >> 6, v = idx & 63;
        out[c * VOX + v0 + v] = tile[c * 65 + v];
    }
}

// LDS layout (float offsets) — unchanged.
#define OFF_XS    0        // 3072  xs[l*48+c]
#define OFF_WDT   3072     // 2496  wdtT[c*52+k]
#define OFF_WB    5568     // 832   wBT[n*52+k]
#define OFF_WC    6400     // 832   wCT[n*52+k]
#define OFF_DTS   7232     // 3264  dtsT[c*68+l]
#define OFF_UX    10496    // 3264  uxT[c*68+l]
#define OFF_BC    13760    // 1088  BcsT[n*68+l]
#define OFF_CC    14848    // 1088  CcsT[n*68+l]
#define OFF_YS    3072     // 3072  ys[l*48+c]  (aliases weights after projections)
#define SMEM_FLOATS 15936  // 63,744 B -> 2 blocks/CU

__global__ __launch_bounds__(768, 6) void k_scan(
    const float* __restrict__ xt, float* __restrict__ yws,
    const float* __restrict__ A_log, const float* __restrict__ W_dt,
    const float* __restrict__ b_dt, const float* __restrict__ W_B,
    const float* __restrict__ W_C, const float* __restrict__ D_skip,
    int dir, int stride_v, int accumulate)
{
    __shared__ __align__(16) float smem[SMEM_FLOATS];
    float* xs   = smem + OFF_XS;
    float* wdtT = smem + OFF_WDT;
    float* wBT  = smem + OFF_WB;
    float* wCT  = smem + OFF_WC;
    float* dtsT = smem + OFF_DTS;
    float* uxT  = smem + OFF_UX;
    float* BcsT = smem + OFF_BC;
    float* CcsT = smem + OFF_CC;
    float* ys   = smem + OFF_YS;

    int t = threadIdx.x;
    int lid = blockIdx.x;
    int a = lid >> 6, b = lid & 63;
    int vbase;
    if (dir == 0) vbase = lid;                 // step stride 4096 (along D)
    else if (dir == 1) vbase = a * 4096 + b;   // step stride 64   (along H)
    else vbase = a * 4096 + b * 64;            // step stride 1    (along W)

    const float* wdt_g = W_dt + dir * CCH * CCH;
    const float* wB_g  = W_B + dir * CCH * NST;
    const float* wC_g  = W_C + dir * CCH * NST;

    // ---- stage line of x (one float4 per thread) ----
    {
        int q = t % 12, l = t / 12;
        *(float4*)&xs[l * CCH + 4 * q] =
            *(const float4*)&xt[(vbase + l * stride_v) * CCH + 4 * q];
    }
    // ---- stage transposed weights ----
    for (int idx = t; idx < CCH * CCH; idx += 768) {
        int k = idx / CCH, c2 = idx - k * CCH;
        wdtT[c2 * 52 + k] = wdt_g[idx];
    }
    {
        int k = t >> 4, n2 = t & 15;
        wBT[n2 * 52 + k] = wB_g[t];
        wCT[n2 * 52 + k] = wC_g[t];
    }
    __syncthreads();

    // ---- fused register-tiled projections: 320 threads, 4 rows x 4 l each ----
    // Identical math to round 6, but ALL accumulators/operands are named
    // scalars (no arrays) so nothing can be demoted to scratch (rule #20).
    if (t < 320) {
        int lq = t & 15;          // l-quad: l = 4*lq + i
        int og = t >> 4;          // output row group
        int lqm = (lq >= 12) ? (lq - 12) : lq;
        const float* wArr;
        float* dst;
        int r0;
        bool isDt = (og < 12);
        if (isDt) { r0 = og * 4; wArr = wdtT; dst = dtsT; }
        else {
            int r = (og - 12) * 4;
            if (r < 16) { wArr = wBT;  dst = BcsT; r0 = r; }
            else        { wArr = wCT;  dst = CcsT; r0 = r - 16; }
        }
        float a00=0.f,a01=0.f,a02=0.f,a03=0.f;
        float a10=0.f,a11=0.f,a12=0.f,a13=0.f;
        float a20=0.f,a21=0.f,a22=0.f,a23=0.f;
        float a30=0.f,a31=0.f,a32=0.f,a33=0.f;
        const float* xrow0 = &xs[(4 * lq + 0) * CCH];
        const float* xrow1 = &xs[(4 * lq + 1) * CCH];
        const float* xrow2 = &xs[(4 * lq + 2) * CCH];
        const float* xrow3 = &xs[(4 * lq + 3) * CCH];
        const float* wrow0 = &wArr[(r0 + 0) * 52];
        const float* wrow1 = &wArr[(r0 + 1) * 52];
        const float* wrow2 = &wArr[(r0 + 2) * 52];
        const float* wrow3 = &wArr[(r0 + 3) * 52];

#define DOT4(A, W, X) \
        A = fmaf(W.x, X.x, A); A = fmaf(W.y, X.y, A); \
        A = fmaf(W.z, X.z, A); A = fmaf(W.w, X.w, A);

#pragma unroll
        for (int q = 0; q < 12; ++q) {
            int qq = q + lqm; if (qq >= 12) qq -= 12;
            int xo = 4 * qq;
            float4 x0 = *(const float4*)&xrow0[xo];
            float4 x1 = *(const float4*)&xrow1[xo];
            float4 x2 = *(const float4*)&xrow2[xo];
            float4 x3 = *(const float4*)&xrow3[xo];
            float4 w0 = *(const float4*)&wrow0[xo];
            float4 w1 = *(const float4*)&wrow1[xo];
            float4 w2 = *(const float4*)&wrow2[xo];
            float4 w3 = *(const float4*)&wrow3[xo];
            DOT4(a00, w0, x0) DOT4(a01, w0, x1) DOT4(a02, w0, x2) DOT4(a03, w0, x3)
            DOT4(a10, w1, x0) DOT4(a11, w1, x1) DOT4(a12, w1, x2) DOT4(a13, w1, x3)
            DOT4(a20, w2, x0) DOT4(a21, w2, x1) DOT4(a22, w2, x2) DOT4(a23, w2, x3)
            DOT4(a30, w3, x0) DOT4(a31, w3, x1) DOT4(a32, w3, x2) DOT4(a33, w3, x3)
        }
#undef DOT4

        if (isDt) {
            float4 xq0 = *(const float4*)&xrow0[r0];
            float4 xq1 = *(const float4*)&xrow1[r0];
            float4 xq2 = *(const float4*)&xrow2[r0];
            float4 xq3 = *(const float4*)&xrow3[r0];
#define EPI(J, CMP, A0, A1, A2, A3)                                  \
            {                                                        \
                float bias = b_dt[dir * CCH + r0 + J];               \
                float4 dtv, uxv;                                     \
                dtv.x = softplus_f(A0 + bias); uxv.x = dtv.x * xq0.CMP; \
                dtv.y = softplus_f(A1 + bias); uxv.y = dtv.y * xq1.CMP; \
                dtv.z = softplus_f(A2 + bias); uxv.z = dtv.z * xq2.CMP; \
                dtv.w = softplus_f(A3 + bias); uxv.w = dtv.w * xq3.CMP; \
                *(float4*)&dtsT[(r0 + J) * 68 + 4 * lq] = dtv;       \
                *(float4*)&uxT[(r0 + J) * 68 + 4 * lq]  = uxv;       \
            }
            EPI(0, x, a00, a01, a02, a03)
            EPI(1, y, a10, a11, a12, a13)
            EPI(2, z, a20, a21, a22, a23)
            EPI(3, w, a30, a31, a32, a33)
#undef EPI
        } else {
            float4 o;
            o.x = a00; o.y = a01; o.z = a02; o.w = a03;
            *(float4*)&dst[(r0 + 0) * 68 + 4 * lq] = o;
            o.x = a10; o.y = a11; o.z = a12; o.w = a13;
            *(float4*)&dst[(r0 + 1) * 68 + 4 * lq] = o;
            o.x = a20; o.y = a21; o.z = a22; o.w = a23;
            *(float4*)&dst[(r0 + 2) * 68 + 4 * lq] = o;
            o.x = a30; o.y = a31; o.z = a32; o.w = a33;
            *(float4*)&dst[(r0 + 3) * 68 + 4 * lq] = o;
        }
    }
    __syncthreads();

    // ---- sequential scan: thread owns state (c,n) ----
    {
        int cc = t >> 4, n = t & 15;
        float a_cn = -expf(A_log[dir * CCH * NST + cc * NST + n]);
        const float4* dt4 = (const float4*)&dtsT[cc * 68];
        const float4* ux4 = (const float4*)&uxT[cc * 68];
        const float4* B4  = (const float4*)&BcsT[n * 68];
        const float4* C4  = (const float4*)&CcsT[n * 68];
        float h = 0.f;

#define STEP(COMP, LIDX)                                                    \
        h = fmaf(__expf(dtv.COMP * a_cn), h, uxv.COMP * Bv.COMP);           \
        {                                                                   \
            float p = h * Cv.COMP;                                          \
            p = dpp_add<0x121>(p);                                          \
            p = dpp_add<0x122>(p);                                          \
            p = dpp_add<0x124>(p);                                          \
            p = dpp_add<0x128>(p);                                          \
            if (n == 0) ys[(LIDX) * CCH + cc] = p;                          \
        }

#pragma unroll
        for (int l4 = 0; l4 < 16; ++l4) {
            float4 dtv = dt4[l4];
            float4 uxv = ux4[l4];
            float4 Bv  = B4[l4];
            float4 Cv  = C4[l4];
            STEP(x, l4 * 4 + 0)
            STEP(y, l4 * 4 + 1)
            STEP(z, l4 * 4 + 2)
            STEP(w, l4 * 4 + 3)
        }
#undef STEP
    }
    __syncthreads();

    // ---- add skip term and write/accumulate to yws ----
    {
        int q = t % 12, l = t / 12;
        float4 yv = *(const float4*)&ys[l * CCH + 4 * q];
        float4 xv = *(const float4*)&xs[l * CCH + 4 * q];
        float4 dv = *(const float4*)&D_skip[dir * CCH + 4 * q];
        yv.x = fmaf(dv.x, xv.x, yv.x);
        yv.y = fmaf(dv.y, xv.y, yv.y);
        yv.z = fmaf(dv.z, xv.z, yv.z);
        yv.w = fmaf(dv.w, xv.w, yv.w);
        float* gp = &yws[(vbase + l * stride_v) * CCH + 4 * q];
        if (accumulate) {
            float4 old = *(const float4*)gp;
            yv.x += old.x; yv.y += old.y; yv.z += old.z; yv.w += old.w;
        }
        *(float4*)gp = yv;
    }
}

extern "C" void kernel_launch(void* const* d_in, const int* in_sizes, int n_in,
                              void* d_out, int out_size, void* d_ws, size_t ws_size,
                              hipStream_t stream) {
    const float* x      = (const float*)d_in[0];
    const float* A_log  = (const float*)d_in[1];
    const float* W_dt   = (const float*)d_in[2];
    const float* b_dt   = (const float*)d_in[3];
    const float* W_B    = (const float*)d_in[4];
    const float* W_C    = (const float*)d_in[5];
    const float* D_skip = (const float*)d_in[6];
    float* out = (float*)d_out;

    float* xt  = (float*)d_ws;
    float* yws = xt + (size_t)VOX * CCH;

    k_transpose_in<<<VOX / 64, 256, 0, stream>>>(x, xt);
    k_scan<<<4096, 768, 0, stream>>>(xt, yws, A_log, W_dt, b_dt, W_B, W_C, D_skip, 0, 4096, 0);
    k_scan<<<4096, 768, 0, stream>>>(xt, yws, A_log, W_dt, b_dt, W_B, W_C, D_skip, 1, 64, 1);
    k_scan<<<4096, 768, 0, stream>>>(xt, yws, A_log, W_dt, b_dt, W_B, W_C, D_skip, 2, 1, 1);
    k_transpose_out<<<VOX / 64, 256, 0, stream>>>(yws, out);
}

// Round 8
// 633.615 us; speedup vs baseline: 1.1547x; 1.0834x over previous
//
#include <hip/hip_runtime.h>
#include <math.h>

#define CCH 48
#define NST 16
#define VOX (64*64*64)

__device__ __forceinline__ float softplus_f(float s) {
    return fmaxf(s, 0.f) + log1pf(__expf(-fabsf(s)));
}

template<int CTRL>
__device__ __forceinline__ float dpp_add(float x) {
    int v = __builtin_amdgcn_update_dpp(0, __float_as_int(x), CTRL, 0xF, 0xF, true);
    return x + __int_as_float(v);
}

__global__ __launch_bounds__(256) void k_transpose_in(const float* __restrict__ x,
                                                      float* __restrict__ xt) {
    __shared__ float tile[CCH * 65];
    int v0 = blockIdx.x * 64;
    int t = threadIdx.x;
#pragma unroll
    for (int i = 0; i < 12; ++i) {
        int idx = t + i * 256;
        int c = idx >> 6, v = idx & 63;
        tile[c * 65 + v] = x[c * VOX + v0 + v];
    }
    __syncthreads();
#pragma unroll
    for (int i = 0; i < 12; ++i) {
        int idx = t + i * 256;
        int v = idx / CCH, c = idx - v * CCH;
        xt[(v0 + v) * CCH + c] = tile[c * 65 + v];
    }
}

__global__ __launch_bounds__(256) void k_transpose_out(const float* __restrict__ yws,
                                                       float* __restrict__ out) {
    __shared__ float tile[CCH * 65];
    int v0 = blockIdx.x * 64;
    int t = threadIdx.x;
#pragma unroll
    for (int i = 0; i < 12; ++i) {
        int idx = t + i * 256;
        int v = idx / CCH, c = idx - v * CCH;
        tile[c * 65 + v] = yws[(v0 + v) * CCH + c];
    }
    __syncthreads();
#pragma unroll
    for (int i = 0; i < 12; ++i) {
        int idx = t + i * 256;
        int c = idx >> 6, v = idx & 63;
        out[c * VOX + v0 + v] = tile[c * 65 + v];
    }
}

// LDS layout (float offsets) — unchanged.
#define OFF_XS    0        // 3072  xs[l*48+c]
#define OFF_WDT   3072     // 2496  wdtT[c*52+k]
#define OFF_WB    5568     // 832   wBT[n*52+k]
#define OFF_WC    6400     // 832   wCT[n*52+k]
#define OFF_DTS   7232     // 3264  dtsT[c*68+l]
#define OFF_UX    10496    // 3264  uxT[c*68+l]
#define OFF_BC    13760    // 1088  BcsT[n*68+l]
#define OFF_CC    14848    // 1088  CcsT[n*68+l]
#define OFF_YS    3072     // 3072  ys[l*48+c]  (aliases weights after projections)
#define SMEM_FLOATS 15936  // 63,744 B -> 2 blocks/CU by LDS

// NOTE launch_bounds: (768,6) capped the allocator at 40 VGPRs (observed:
// VGPR_Count=40 + 233MB scratch writebacks in rounds 6-7). (768,2) caps at
// >=85 under either arg-2 semantics; compiler lands ~60 -> still 2 blocks/CU.
__global__ __launch_bounds__(768, 2) void k_scan(
    const float* __restrict__ xt, float* __restrict__ yws,
    const float* __restrict__ A_log, const float* __restrict__ W_dt,
    const float* __restrict__ b_dt, const float* __restrict__ W_B,
    const float* __restrict__ W_C, const float* __restrict__ D_skip,
    int dir, int stride_v, int accumulate)
{
    __shared__ __align__(16) float smem[SMEM_FLOATS];
    float* xs   = smem + OFF_XS;
    float* wdtT = smem + OFF_WDT;
    float* wBT  = smem + OFF_WB;
    float* wCT  = smem + OFF_WC;
    float* dtsT = smem + OFF_DTS;
    float* uxT  = smem + OFF_UX;
    float* BcsT = smem + OFF_BC;
    float* CcsT = smem + OFF_CC;
    float* ys   = smem + OFF_YS;

    int t = threadIdx.x;
    int lid = blockIdx.x;
    int a = lid >> 6, b = lid & 63;
    int vbase;
    if (dir == 0) vbase = lid;                 // step stride 4096 (along D)
    else if (dir == 1) vbase = a * 4096 + b;   // step stride 64   (along H)
    else vbase = a * 4096 + b * 64;            // step stride 1    (along W)

    const float* wdt_g = W_dt + dir * CCH * CCH;
    const float* wB_g  = W_B + dir * CCH * NST;
    const float* wC_g  = W_C + dir * CCH * NST;

    // ---- stage line of x (one float4 per thread) ----
    {
        int q = t % 12, l = t / 12;
        *(float4*)&xs[l * CCH + 4 * q] =
            *(const float4*)&xt[(vbase + l * stride_v) * CCH + 4 * q];
    }
    // ---- stage transposed weights ----
    for (int idx = t; idx < CCH * CCH; idx += 768) {
        int k = idx / CCH, c2 = idx - k * CCH;
        wdtT[c2 * 52 + k] = wdt_g[idx];
    }
    {
        int k = t >> 4, n2 = t & 15;
        wBT[n2 * 52 + k] = wB_g[t];
        wCT[n2 * 52 + k] = wC_g[t];
    }
    __syncthreads();

    // ---- fused register-tiled projections: 320 threads, 4 rows x 4 l each.
    // One w-row live at a time: live set ~ 16(x) + 4(w) + 16(acc) regs.
    if (t < 320) {
        int lq = t & 15;          // l-quad: l = 4*lq + i
        int og = t >> 4;          // output row group
        int lqm = (lq >= 12) ? (lq - 12) : lq;
        const float* wArr;
        float* dst;
        int r0;
        bool isDt = (og < 12);
        if (isDt) { r0 = og * 4; wArr = wdtT; dst = dtsT; }
        else {
            int r = (og - 12) * 4;
            if (r < 16) { wArr = wBT;  dst = BcsT; r0 = r; }
            else        { wArr = wCT;  dst = CcsT; r0 = r - 16; }
        }
        float a00=0.f,a01=0.f,a02=0.f,a03=0.f;
        float a10=0.f,a11=0.f,a12=0.f,a13=0.f;
        float a20=0.f,a21=0.f,a22=0.f,a23=0.f;
        float a30=0.f,a31=0.f,a32=0.f,a33=0.f;
        const float* xrow0 = &xs[(4 * lq + 0) * CCH];
        const float* xrow1 = &xs[(4 * lq + 1) * CCH];
        const float* xrow2 = &xs[(4 * lq + 2) * CCH];
        const float* xrow3 = &xs[(4 * lq + 3) * CCH];
        const float* wbase = &wArr[r0 * 52];

#define DOT4(A, W, X) \
        A = fmaf(W.x, X.x, A); A = fmaf(W.y, X.y, A); \
        A = fmaf(W.z, X.z, A); A = fmaf(W.w, X.w, A);

#pragma unroll
        for (int q = 0; q < 12; ++q) {
            int qq = q + lqm; if (qq >= 12) qq -= 12;
            int xo = 4 * qq;
            float4 x0 = *(const float4*)&xrow0[xo];
            float4 x1 = *(const float4*)&xrow1[xo];
            float4 x2 = *(const float4*)&xrow2[xo];
            float4 x3 = *(const float4*)&xrow3[xo];
            float4 w;
            w = *(const float4*)&wbase[0 * 52 + xo];
            DOT4(a00, w, x0) DOT4(a01, w, x1) DOT4(a02, w, x2) DOT4(a03, w, x3)
            w = *(const float4*)&wbase[1 * 52 + xo];
            DOT4(a10, w, x0) DOT4(a11, w, x1) DOT4(a12, w, x2) DOT4(a13, w, x3)
            w = *(const float4*)&wbase[2 * 52 + xo];
            DOT4(a20, w, x0) DOT4(a21, w, x1) DOT4(a22, w, x2) DOT4(a23, w, x3)
            w = *(const float4*)&wbase[3 * 52 + xo];
            DOT4(a30, w, x0) DOT4(a31, w, x1) DOT4(a32, w, x2) DOT4(a33, w, x3)
        }
#undef DOT4

        if (isDt) {
            float4 xq0 = *(const float4*)&xrow0[r0];
            float4 xq1 = *(const float4*)&xrow1[r0];
            float4 xq2 = *(const float4*)&xrow2[r0];
            float4 xq3 = *(const float4*)&xrow3[r0];
#define EPI(J, CMP, A0, A1, A2, A3)                                  \
            {                                                        \
                float bias = b_dt[dir * CCH + r0 + J];               \
                float4 dtv, uxv;                                     \
                dtv.x = softplus_f(A0 + bias); uxv.x = dtv.x * xq0.CMP; \
                dtv.y = softplus_f(A1 + bias); uxv.y = dtv.y * xq1.CMP; \
                dtv.z = softplus_f(A2 + bias); uxv.z = dtv.z * xq2.CMP; \
                dtv.w = softplus_f(A3 + bias); uxv.w = dtv.w * xq3.CMP; \
                *(float4*)&dtsT[(r0 + J) * 68 + 4 * lq] = dtv;       \
                *(float4*)&uxT[(r0 + J) * 68 + 4 * lq]  = uxv;       \
            }
            EPI(0, x, a00, a01, a02, a03)
            EPI(1, y, a10, a11, a12, a13)
            EPI(2, z, a20, a21, a22, a23)
            EPI(3, w, a30, a31, a32, a33)
#undef EPI
        } else {
            float4 o;
            o.x = a00; o.y = a01; o.z = a02; o.w = a03;
            *(float4*)&dst[(r0 + 0) * 68 + 4 * lq] = o;
            o.x = a10; o.y = a11; o.z = a12; o.w = a13;
            *(float4*)&dst[(r0 + 1) * 68 + 4 * lq] = o;
            o.x = a20; o.y = a21; o.z = a22; o.w = a23;
            *(float4*)&dst[(r0 + 2) * 68 + 4 * lq] = o;
            o.x = a30; o.y = a31; o.z = a32; o.w = a33;
            *(float4*)&dst[(r0 + 3) * 68 + 4 * lq] = o;
        }
    }
    __syncthreads();

    // ---- sequential scan: thread owns state (c,n) ----
    {
        int cc = t >> 4, n = t & 15;
        float a_cn = -expf(A_log[dir * CCH * NST + cc * NST + n]);
        const float4* dt4 = (const float4*)&dtsT[cc * 68];
        const float4* ux4 = (const float4*)&uxT[cc * 68];
        const float4* B4  = (const float4*)&BcsT[n * 68];
        const float4* C4  = (const float4*)&CcsT[n * 68];
        float h = 0.f;

#define STEP(COMP, LIDX)                                                    \
        h = fmaf(__expf(dtv.COMP * a_cn), h, uxv.COMP * Bv.COMP);           \
        {                                                                   \
            float p = h * Cv.COMP;                                          \
            p = dpp_add<0x121>(p);                                          \
            p = dpp_add<0x122>(p);                                          \
            p = dpp_add<0x124>(p);                                          \
            p = dpp_add<0x128>(p);                                          \
            if (n == 0) ys[(LIDX) * CCH + cc] = p;                          \
        }

#pragma unroll
        for (int l4 = 0; l4 < 16; ++l4) {
            float4 dtv = dt4[l4];
            float4 uxv = ux4[l4];
            float4 Bv  = B4[l4];
            float4 Cv  = C4[l4];
            STEP(x, l4 * 4 + 0)
            STEP(y, l4 * 4 + 1)
            STEP(z, l4 * 4 + 2)
            STEP(w, l4 * 4 + 3)
        }
#undef STEP
    }
    __syncthreads();

    // ---- add skip term and write/accumulate to yws ----
    {
        int q = t % 12, l = t / 12;
        float4 yv = *(const float4*)&ys[l * CCH + 4 * q];
        float4 xv = *(const float4*)&xs[l * CCH + 4 * q];
        float4 dv = *(const float4*)&D_skip[dir * CCH + 4 * q];
        yv.x = fmaf(dv.x, xv.x, yv.x);
        yv.y = fmaf(dv.y, xv.y, yv.y);
        yv.z = fmaf(dv.z, xv.z, yv.z);
        yv.w = fmaf(dv.w, xv.w, yv.w);
        float* gp = &yws[(vbase + l * stride_v) * CCH + 4 * q];
        if (accumulate) {
            float4 old = *(const float4*)gp;
            yv.x += old.x; yv.y += old.y; yv.z += old.z; yv.w += old.w;
        }
        *(float4*)gp = yv;
    }
}

extern "C" void kernel_launch(void* const* d_in, const int* in_sizes, int n_in,
                              void* d_out, int out_size, void* d_ws, size_t ws_size,
                              hipStream_t stream) {
    const float* x      = (const float*)d_in[0];
    const float* A_log  = (const float*)d_in[1];
    const float* W_dt   = (const float*)d_in[2];
    const float* b_dt   = (const float*)d_in[3];
    const float* W_B    = (const float*)d_in[4];
    const float* W_C    = (const float*)d_in[5];
    const float* D_skip = (const float*)d_in[6];
    float* out = (float*)d_out;

    float* xt  = (float*)d_ws;
    float* yws = xt + (size_t)VOX * CCH;

    k_transpose_in<<<VOX / 64, 256, 0, stream>>>(x, xt);
    k_scan<<<4096, 768, 0, stream>>>(xt, yws, A_log, W_dt, b_dt, W_B, W_C, D_skip, 0, 4096, 0);
    k_scan<<<4096, 768, 0, stream>>>(xt, yws, A_log, W_dt, b_dt, W_B, W_C, D_skip, 1, 64, 1);
    k_scan<<<4096, 768, 0, stream>>>(xt, yws, A_log, W_dt, b_dt, W_B, W_C, D_skip, 2, 1, 1);
    k_transpose_out<<<VOX / 64, 256, 0, stream>>>(yws, out);
}

// Round 9
// 633.285 us; speedup vs baseline: 1.1553x; 1.0005x over previous
//
#include <hip/hip_runtime.h>
#include <math.h>

#define CCH 48
#define NST 16
#define VOX (64*64*64)

__device__ __forceinline__ float softplus_f(float s) {
    return fmaxf(s, 0.f) + log1pf(__expf(-fabsf(s)));
}

template<int CTRL>
__device__ __forceinline__ float dpp_add(float x) {
    int v = __builtin_amdgcn_update_dpp(0, __float_as_int(x), CTRL, 0xF, 0xF, true);
    return x + __int_as_float(v);
}

__global__ __launch_bounds__(256) void k_transpose_in(const float* __restrict__ x,
                                                      float* __restrict__ xt) {
    __shared__ float tile[CCH * 65];
    int v0 = blockIdx.x * 64;
    int t = threadIdx.x;
#pragma unroll
    for (int i = 0; i < 12; ++i) {
        int idx = t + i * 256;
        int c = idx >> 6, v = idx & 63;
        tile[c * 65 + v] = x[c * VOX + v0 + v];
    }
    __syncthreads();
#pragma unroll
    for (int i = 0; i < 12; ++i) {
        int idx = t + i * 256;
        int v = idx / CCH, c = idx - v * CCH;
        xt[(v0 + v) * CCH + c] = tile[c * 65 + v];
    }
}

__global__ __launch_bounds__(256) void k_transpose_out(const float* __restrict__ yws,
                                                       float* __restrict__ out) {
    __shared__ float tile[CCH * 65];
    int v0 = blockIdx.x * 64;
    int t = threadIdx.x;
#pragma unroll
    for (int i = 0; i < 12; ++i) {
        int idx = t + i * 256;
        int v = idx / CCH, c = idx - v * CCH;
        tile[c * 65 + v] = yws[(v0 + v) * CCH + c];
    }
    __syncthreads();
#pragma unroll
    for (int i = 0; i < 12; ++i) {
        int idx = t + i * 256;
        int c = idx >> 6, v = idx & 63;
        out[c * VOX + v0 + v] = tile[c * 65 + v];
    }
}

// LDS layout (float offsets) — unchanged.
#define OFF_XS    0        // 3072  xs[l*48+c]
#define OFF_WDT   3072     // 2496  wdtT[c*52+k]
#define OFF_WB    5568     // 832   wBT[n*52+k]
#define OFF_WC    6400     // 832   wCT[n*52+k]
#define OFF_DTS   7232     // 3264  dtsT[c*68+l]
#define OFF_UX    10496    // 3264  uxT[c*68+l]
#define OFF_BC    13760    // 1088  BcsT[n*68+l]
#define OFF_CC    14848    // 1088  CcsT[n*68+l]
#define OFF_YS    3072     // 3072  ys[l*48+c]  (aliases weights after projections)
#define SMEM_FLOATS 15936  // 63,744 B -> 2 blocks/CU by LDS

// launch_bounds history (keep!):
//  (768,6): RA capped at 40 VGPR -> 233MB scratch spill (rounds 6-7).
//  (768,2): RA landed 64 VGPR, no spill, BUT vgpr=64 crosses the waves/CU
//           halving boundary (m69) -> 16-wave cap -> 1 block/CU,
//           Occupancy 34.5%, k_scan 224us (round 8).
//  (768,4): target ~60-VGPR budget: <64 keeps 2 blocks/CU, >55 avoids spill.
__global__ __launch_bounds__(768, 4) void k_scan(
    const float* __restrict__ xt, float* __restrict__ yws,
    const float* __restrict__ A_log, const float* __restrict__ W_dt,
    const float* __restrict__ b_dt, const float* __restrict__ W_B,
    const float* __restrict__ W_C, const float* __restrict__ D_skip,
    int dir, int stride_v, int accumulate)
{
    __shared__ __align__(16) float smem[SMEM_FLOATS];
    float* xs   = smem + OFF_XS;
    float* wdtT = smem + OFF_WDT;
    float* wBT  = smem + OFF_WB;
    float* wCT  = smem + OFF_WC;
    float* dtsT = smem + OFF_DTS;
    float* uxT  = smem + OFF_UX;
    float* BcsT = smem + OFF_BC;
    float* CcsT = smem + OFF_CC;
    float* ys   = smem + OFF_YS;

    int t = threadIdx.x;
    int lid = blockIdx.x;
    int a = lid >> 6, b = lid & 63;
    int vbase;
    if (dir == 0) vbase = lid;                 // step stride 4096 (along D)
    else if (dir == 1) vbase = a * 4096 + b;   // step stride 64   (along H)
    else vbase = a * 4096 + b * 64;            // step stride 1    (along W)

    const float* wdt_g = W_dt + dir * CCH * CCH;
    const float* wB_g  = W_B + dir * CCH * NST;
    const float* wC_g  = W_C + dir * CCH * NST;

    // ---- stage line of x (one float4 per thread) ----
    {
        int q = t % 12, l = t / 12;
        *(float4*)&xs[l * CCH + 4 * q] =
            *(const float4*)&xt[(vbase + l * stride_v) * CCH + 4 * q];
    }
    // ---- stage transposed weights ----
    for (int idx = t; idx < CCH * CCH; idx += 768) {
        int k = idx / CCH, c2 = idx - k * CCH;
        wdtT[c2 * 52 + k] = wdt_g[idx];
    }
    {
        int k = t >> 4, n2 = t & 15;
        wBT[n2 * 52 + k] = wB_g[t];
        wCT[n2 * 52 + k] = wC_g[t];
    }
    __syncthreads();

    // ---- fused register-tiled projections: 320 threads, 4 rows x 4 l each.
    // One w-row live at a time: live set ~ 16(x) + 4(w) + 16(acc) regs.
    if (t < 320) {
        int lq = t & 15;          // l-quad: l = 4*lq + i
        int og = t >> 4;          // output row group
        int lqm = (lq >= 12) ? (lq - 12) : lq;
        const float* wArr;
        float* dst;
        int r0;
        bool isDt = (og < 12);
        if (isDt) { r0 = og * 4; wArr = wdtT; dst = dtsT; }
        else {
            int r = (og - 12) * 4;
            if (r < 16) { wArr = wBT;  dst = BcsT; r0 = r; }
            else        { wArr = wCT;  dst = CcsT; r0 = r - 16; }
        }
        float a00=0.f,a01=0.f,a02=0.f,a03=0.f;
        float a10=0.f,a11=0.f,a12=0.f,a13=0.f;
        float a20=0.f,a21=0.f,a22=0.f,a23=0.f;
        float a30=0.f,a31=0.f,a32=0.f,a33=0.f;
        const float* xrow0 = &xs[(4 * lq + 0) * CCH];
        const float* xrow1 = &xs[(4 * lq + 1) * CCH];
        const float* xrow2 = &xs[(4 * lq + 2) * CCH];
        const float* xrow3 = &xs[(4 * lq + 3) * CCH];
        const float* wbase = &wArr[r0 * 52];

#define DOT4(A, W, X) \
        A = fmaf(W.x, X.x, A); A = fmaf(W.y, X.y, A); \
        A = fmaf(W.z, X.z, A); A = fmaf(W.w, X.w, A);

#pragma unroll
        for (int q = 0; q < 12; ++q) {
            int qq = q + lqm; if (qq >= 12) qq -= 12;
            int xo = 4 * qq;
            float4 x0 = *(const float4*)&xrow0[xo];
            float4 x1 = *(const float4*)&xrow1[xo];
            float4 x2 = *(const float4*)&xrow2[xo];
            float4 x3 = *(const float4*)&xrow3[xo];
            float4 w;
            w = *(const float4*)&wbase[0 * 52 + xo];
            DOT4(a00, w, x0) DOT4(a01, w, x1) DOT4(a02, w, x2) DOT4(a03, w, x3)
            w = *(const float4*)&wbase[1 * 52 + xo];
            DOT4(a10, w, x0) DOT4(a11, w, x1) DOT4(a12, w, x2) DOT4(a13, w, x3)
            w = *(const float4*)&wbase[2 * 52 + xo];
            DOT4(a20, w, x0) DOT4(a21, w, x1) DOT4(a22, w, x2) DOT4(a23, w, x3)
            w = *(const float4*)&wbase[3 * 52 + xo];
            DOT4(a30, w, x0) DOT4(a31, w, x1) DOT4(a32, w, x2) DOT4(a33, w, x3)
        }
#undef DOT4

        if (isDt) {
            float4 xq0 = *(const float4*)&xrow0[r0];
            float4 xq1 = *(const float4*)&xrow1[r0];
            float4 xq2 = *(const float4*)&xrow2[r0];
            float4 xq3 = *(const float4*)&xrow3[r0];
#define EPI(J, CMP, A0, A1, A2, A3)                                  \
            {                                                        \
                float bias = b_dt[dir * CCH + r0 + J];               \
                float4 dtv, uxv;                                     \
                dtv.x = softplus_f(A0 + bias); uxv.x = dtv.x * xq0.CMP; \
                dtv.y = softplus_f(A1 + bias); uxv.y = dtv.y * xq1.CMP; \
                dtv.z = softplus_f(A2 + bias); uxv.z = dtv.z * xq2.CMP; \
                dtv.w = softplus_f(A3 + bias); uxv.w = dtv.w * xq3.CMP; \
                *(float4*)&dtsT[(r0 + J) * 68 + 4 * lq] = dtv;       \
                *(float4*)&uxT[(r0 + J) * 68 + 4 * lq]  = uxv;       \
            }
            EPI(0, x, a00, a01, a02, a03)
            EPI(1, y, a10, a11, a12, a13)
            EPI(2, z, a20, a21, a22, a23)
            EPI(3, w, a30, a31, a32, a33)
#undef EPI
        } else {
            float4 o;
            o.x = a00; o.y = a01; o.z = a02; o.w = a03;
            *(float4*)&dst[(r0 + 0) * 68 + 4 * lq] = o;
            o.x = a10; o.y = a11; o.z = a12; o.w = a13;
            *(float4*)&dst[(r0 + 1) * 68 + 4 * lq] = o;
            o.x = a20; o.y = a21; o.z = a22; o.w = a23;
            *(float4*)&dst[(r0 + 2) * 68 + 4 * lq] = o;
            o.x = a30; o.y = a31; o.z = a32; o.w = a33;
            *(float4*)&dst[(r0 + 3) * 68 + 4 * lq] = o;
        }
    }
    __syncthreads();

    // ---- sequential scan: thread owns state (c,n) ----
    {
        int cc = t >> 4, n = t & 15;
        float a_cn = -expf(A_log[dir * CCH * NST + cc * NST + n]);
        const float4* dt4 = (const float4*)&dtsT[cc * 68];
        const float4* ux4 = (const float4*)&uxT[cc * 68];
        const float4* B4  = (const float4*)&BcsT[n * 68];
        const float4* C4  = (const float4*)&CcsT[n * 68];
        float h = 0.f;

#define STEP(COMP, LIDX)                                                    \
        h = fmaf(__expf(dtv.COMP * a_cn), h, uxv.COMP * Bv.COMP);           \
        {                                                                   \
            float p = h * Cv.COMP;                                          \
            p = dpp_add<0x121>(p);                                          \
            p = dpp_add<0x122>(p);                                          \
            p = dpp_add<0x124>(p);                                          \
            p = dpp_add<0x128>(p);                                          \
            if (n == 0) ys[(LIDX) * CCH + cc] = p;                          \
        }

#pragma unroll
        for (int l4 = 0; l4 < 16; ++l4) {
            float4 dtv = dt4[l4];
            float4 uxv = ux4[l4];
            float4 Bv  = B4[l4];
            float4 Cv  = C4[l4];
            STEP(x, l4 * 4 + 0)
            STEP(y, l4 * 4 + 1)
            STEP(z, l4 * 4 + 2)
            STEP(w, l4 * 4 + 3)
        }
#undef STEP
    }
    __syncthreads();

    // ---- add skip term and write/accumulate to yws ----
    {
        int q = t % 12, l = t / 12;
        float4 yv = *(const float4*)&ys[l * CCH + 4 * q];
        float4 xv = *(const float4*)&xs[l * CCH + 4 * q];
        float4 dv = *(const float4*)&D_skip[dir * CCH + 4 * q];
        yv.x = fmaf(dv.x, xv.x, yv.x);
        yv.y = fmaf(dv.y, xv.y, yv.y);
        yv.z = fmaf(dv.z, xv.z, yv.z);
        yv.w = fmaf(dv.w, xv.w, yv.w);
        float* gp = &yws[(vbase + l * stride_v) * CCH + 4 * q];
        if (accumulate) {
            float4 old = *(const float4*)gp;
            yv.x += old.x; yv.y += old.y; yv.z += old.z; yv.w += old.w;
        }
        *(float4*)gp = yv;
    }
}

extern "C" void kernel_launch(void* const* d_in, const int* in_sizes, int n_in,
                              void* d_out, int out_size, void* d_ws, size_t ws_size,
                              hipStream_t stream) {
    const float* x      = (const float*)d_in[0];
    const float* A_log  = (const float*)d_in[1];
    const float* W_dt   = (const float*)d_in[2];
    const float* b_dt   = (const float*)d_in[3];
    const float* W_B    = (const float*)d_in[4];
    const float* W_C    = (const float*)d_in[5];
    const float* D_skip = (const float*)d_in[6];
    float* out = (float*)d_out;

    float* xt  = (float*)d_ws;
    float* yws = xt + (size_t)VOX * CCH;

    k_transpose_in<<<VOX / 64, 256, 0, stream>>>(x, xt);
    k_scan<<<4096, 768, 0, stream>>>(xt, yws, A_log, W_dt, b_dt, W_B, W_C, D_skip, 0, 4096, 0);
    k_scan<<<4096, 768, 0, stream>>>(xt, yws, A_log, W_dt, b_dt, W_B, W_C, D_skip, 1, 64, 1);
    k_scan<<<4096, 768, 0, stream>>>(xt, yws, A_log, W_dt, b_dt, W_B, W_C, D_skip, 2, 1, 1);
    k_transpose_out<<<VOX / 64, 256, 0, stream>>>(yws, out);
}

// Round 11
// 505.122 us; speedup vs baseline: 1.4484x; 1.2537x over previous
//
#include <hip/hip_runtime.h>
#include <math.h>

#define CCH 48
#define NST 16
#define VOX (64*64*64)

__device__ __forceinline__ float softplus_f(float s) {
    return fmaxf(s, 0.f) + log1pf(__expf(-fabsf(s)));
}

template<int CTRL>
__device__ __forceinline__ float dpp_add(float x) {
    int v = __builtin_amdgcn_update_dpp(0, __float_as_int(x), CTRL, 0xF, 0xF, true);
    return x + __int_as_float(v);
}

__global__ __launch_bounds__(256) void k_transpose_in(const float* __restrict__ x,
                                                      float* __restrict__ xt) {
    __shared__ float tile[CCH * 65];
    int v0 = blockIdx.x * 64;
    int t = threadIdx.x;
#pragma unroll
    for (int i = 0; i < 12; ++i) {
        int idx = t + i * 256;
        int c = idx >> 6, v = idx & 63;
        tile[c * 65 + v] = x[c * VOX + v0 + v];
    }
    __syncthreads();
#pragma unroll
    for (int i = 0; i < 12; ++i) {
        int idx = t + i * 256;
        int v = idx / CCH, c = idx - v * CCH;
        xt[(v0 + v) * CCH + c] = tile[c * 65 + v];
    }
}

__global__ __launch_bounds__(256) void k_transpose_out(const float* __restrict__ yws,
                                                       float* __restrict__ out) {
    __shared__ float tile[CCH * 65];
    int v0 = blockIdx.x * 64;
    int t = threadIdx.x;
#pragma unroll
    for (int i = 0; i < 12; ++i) {
        int idx = t + i * 256;
        int v = idx / CCH, c = idx - v * CCH;
        tile[c * 65 + v] = yws[(v0 + v) * CCH + c];
    }
    __syncthreads();
#pragma unroll
    for (int i = 0; i < 12; ++i) {
        int idx = t + i * 256;
        int c = idx >> 6, v = idx & 63;
        out[c * VOX + v0 + v] = tile[c * 65 + v];
    }
}

// LDS layout (float offsets) — unchanged since round 5.
#define OFF_XS    0        // 3072  xs[l*48+c]
#define OFF_WDT   3072     // 2496  wdtT[c*52+k]
#define OFF_WB    5568     // 832   wBT[n*52+k]
#define OFF_WC    6400     // 832   wCT[n*52+k]
#define OFF_DTS   7232     // 3264  dtsT[c*68+l]
#define OFF_UX    10496    // 3264  uxT[c*68+l]
#define OFF_BC    13760    // 1088  BcsT[n*68+l]
#define OFF_CC    14848    // 1088  CcsT[n*68+l]
#define OFF_YS    3072     // 3072  ys[l*48+c]  (aliases weights after projections)
#define SMEM_FLOATS 15936  // 63,744 B -> 2 blocks/CU by LDS

// launch_bounds ledger (empirical, this kernel):
//  arg2=6 -> RA cap 40 VGPR (r3-r7): fine IF live-set fits, else scratch spill.
//  arg2=4/2 -> cap 64; VGPR=64 crosses the waves/CU halving boundary (m69)
//            -> 1 block/CU, Occ 34%, ~1.9x latency factor (r8/r9).
//  => keep (768,6) and design every phase for live-set <= ~32 regs.
// Cross-lane ledger:
//  dpp row_ror {1,2,4,8} full-16 reduce: correct (r5, direction-agnostic).
//  dpp row_ror {1,2,4} 8-lane window: WRONG (r10, direction-dependent wrap).
__global__ __launch_bounds__(768, 6) void k_scan(
    const float* __restrict__ xt, float* __restrict__ yws,
    const float* __restrict__ A_log, const float* __restrict__ W_dt,
    const float* __restrict__ b_dt, const float* __restrict__ W_B,
    const float* __restrict__ W_C, const float* __restrict__ D_skip,
    int dir, int stride_v, int accumulate)
{
    __shared__ __align__(16) float smem[SMEM_FLOATS];
    float* xs   = smem + OFF_XS;
    float* wdtT = smem + OFF_WDT;
    float* wBT  = smem + OFF_WB;
    float* wCT  = smem + OFF_WC;
    float* dtsT = smem + OFF_DTS;
    float* uxT  = smem + OFF_UX;
    float* BcsT = smem + OFF_BC;
    float* CcsT = smem + OFF_CC;
    float* ys   = smem + OFF_YS;

    int t = threadIdx.x;
    int lid = blockIdx.x;
    int a = lid >> 6, b = lid & 63;
    int vbase;
    if (dir == 0) vbase = lid;                 // step stride 4096 (along D)
    else if (dir == 1) vbase = a * 4096 + b;   // step stride 64   (along H)
    else vbase = a * 4096 + b * 64;            // step stride 1    (along W)

    const float* wdt_g = W_dt + dir * CCH * CCH;
    const float* wB_g  = W_B + dir * CCH * NST;
    const float* wC_g  = W_C + dir * CCH * NST;

    // ---- stage line of x (one float4 per thread) ----
    {
        int q = t % 12, l = t / 12;
        *(float4*)&xs[l * CCH + 4 * q] =
            *(const float4*)&xt[(vbase + l * stride_v) * CCH + 4 * q];
    }
    // ---- stage transposed weights ----
    for (int idx = t; idx < CCH * CCH; idx += 768) {
        int k = idx / CCH, c2 = idx - k * CCH;
        wdtT[c2 * 52 + k] = wdt_g[idx];
    }
    {
        int k = t >> 4, n2 = t & 15;
        wBT[n2 * 52 + k] = wB_g[t];
        wCT[n2 * 52 + k] = wC_g[t];
    }
    __syncthreads();

    // ---- projections: 320 threads, 4 rows x 4 l, TWO passes of 4x2 ----
    // Live set per pass: 8 acc + 8 x + 4 w + addressing ~= 30 regs (< 40 cap).
    // qq rotation spreads the lq-strided x reads across banks.
    if (t < 320) {
        int lq = t & 15;          // l-quad: l = 4*lq + i, i=0..3
        int og = t >> 4;          // output row group
        int lqm = (lq >= 12) ? (lq - 12) : lq;
        const float* wArr;
        float* dst;
        int r0;
        bool isDt = (og < 12);
        if (isDt) { r0 = og * 4; wArr = wdtT; dst = dtsT; }
        else {
            int r = (og - 12) * 4;
            if (r < 16) { wArr = wBT;  dst = BcsT; r0 = r; }
            else        { wArr = wCT;  dst = CcsT; r0 = r - 16; }
        }
        const float* wbase = &wArr[r0 * 52];

#define DOT4(A, W, X) \
        A = fmaf(W.x, X.x, A); A = fmaf(W.y, X.y, A); \
        A = fmaf(W.z, X.z, A); A = fmaf(W.w, X.w, A);

#pragma unroll
        for (int pass = 0; pass < 2; ++pass) {
            int i0 = 2 * pass;
            const float* xrowA = &xs[(4 * lq + i0 + 0) * CCH];
            const float* xrowB = &xs[(4 * lq + i0 + 1) * CCH];
            float b0a=0.f,b0b=0.f, b1a=0.f,b1b=0.f;
            float b2a=0.f,b2b=0.f, b3a=0.f,b3b=0.f;
#pragma unroll
            for (int q = 0; q < 12; ++q) {
                int qq = q + lqm; if (qq >= 12) qq -= 12;
                int xo = 4 * qq;
                float4 xA = *(const float4*)&xrowA[xo];
                float4 xB = *(const float4*)&xrowB[xo];
                float4 w;
                w = *(const float4*)&wbase[0 * 52 + xo];
                DOT4(b0a, w, xA) DOT4(b0b, w, xB)
                w = *(const float4*)&wbase[1 * 52 + xo];
                DOT4(b1a, w, xA) DOT4(b1b, w, xB)
                w = *(const float4*)&wbase[2 * 52 + xo];
                DOT4(b2a, w, xA) DOT4(b2b, w, xB)
                w = *(const float4*)&wbase[3 * 52 + xo];
                DOT4(b3a, w, xA) DOT4(b3b, w, xB)
            }
            if (isDt) {
#define EPI(J, SA, SB)                                                    \
                {                                                         \
                    float bias = b_dt[dir * CCH + r0 + J];                \
                    float xa = xrowA[r0 + J];                             \
                    float xb = xrowB[r0 + J];                             \
                    float2 dtv, uxv;                                      \
                    dtv.x = softplus_f(SA + bias); uxv.x = dtv.x * xa;    \
                    dtv.y = softplus_f(SB + bias); uxv.y = dtv.y * xb;    \
                    *(float2*)&dtsT[(r0 + J) * 68 + 4 * lq + i0] = dtv;   \
                    *(float2*)&uxT[(r0 + J) * 68 + 4 * lq + i0]  = uxv;   \
                }
                EPI(0, b0a, b0b)
                EPI(1, b1a, b1b)
                EPI(2, b2a, b2b)
                EPI(3, b3a, b3b)
#undef EPI
            } else {
                float2 o;
                o.x = b0a; o.y = b0b; *(float2*)&dst[(r0 + 0) * 68 + 4 * lq + i0] = o;
                o.x = b1a; o.y = b1b; *(float2*)&dst[(r0 + 1) * 68 + 4 * lq + i0] = o;
                o.x = b2a; o.y = b2b; *(float2*)&dst[(r0 + 2) * 68 + 4 * lq + i0] = o;
                o.x = b3a; o.y = b3b; *(float2*)&dst[(r0 + 3) * 68 + 4 * lq + i0] = o;
            }
        }
#undef DOT4
    }
    __syncthreads();

    // ---- sequential scan: thread owns state (c,n) — round-5 proven form ----
    {
        int cc = t >> 4, n = t & 15;
        float a_cn = -expf(A_log[dir * CCH * NST + cc * NST + n]);
        const float4* dt4 = (const float4*)&dtsT[cc * 68];
        const float4* ux4 = (const float4*)&uxT[cc * 68];
        const float4* B4  = (const float4*)&BcsT[n * 68];
        const float4* C4  = (const float4*)&CcsT[n * 68];
        float h = 0.f;

#define STEP(COMP, LIDX)                                                    \
        h = fmaf(__expf(dtv.COMP * a_cn), h, uxv.COMP * Bv.COMP);           \
        {                                                                   \
            float p = h * Cv.COMP;                                          \
            p = dpp_add<0x121>(p);                                          \
            p = dpp_add<0x122>(p);                                          \
            p = dpp_add<0x124>(p);                                          \
            p = dpp_add<0x128>(p);                                          \
            if (n == 0) ys[(LIDX) * CCH + cc] = p;                          \
        }

#pragma unroll
        for (int l4 = 0; l4 < 16; ++l4) {
            float4 dtv = dt4[l4];
            float4 uxv = ux4[l4];
            float4 Bv  = B4[l4];
            float4 Cv  = C4[l4];
            STEP(x, l4 * 4 + 0)
            STEP(y, l4 * 4 + 1)
            STEP(z, l4 * 4 + 2)
            STEP(w, l4 * 4 + 3)
        }
#undef STEP
    }
    __syncthreads();

    // ---- add skip term and write/accumulate to yws ----
    {
        int q = t % 12, l = t / 12;
        float4 yv = *(const float4*)&ys[l * CCH + 4 * q];
        float4 xv = *(const float4*)&xs[l * CCH + 4 * q];
        float4 dv = *(const float4*)&D_skip[dir * CCH + 4 * q];
        yv.x = fmaf(dv.x, xv.x, yv.x);
        yv.y = fmaf(dv.y, xv.y, yv.y);
        yv.z = fmaf(dv.z, xv.z, yv.z);
        yv.w = fmaf(dv.w, xv.w, yv.w);
        float* gp = &yws[(vbase + l * stride_v) * CCH + 4 * q];
        if (accumulate) {
            float4 old = *(const float4*)gp;
            yv.x += old.x; yv.y += old.y; yv.z += old.z; yv.w += old.w;
        }
        *(float4*)gp = yv;
    }
}

extern "C" void kernel_launch(void* const* d_in, const int* in_sizes, int n_in,
                              void* d_out, int out_size, void* d_ws, size_t ws_size,
                              hipStream_t stream) {
    const float* x      = (const float*)d_in[0];
    const float* A_log  = (const float*)d_in[1];
    const float* W_dt   = (const float*)d_in[2];
    const float* b_dt   = (const float*)d_in[3];
    const float* W_B    = (const float*)d_in[4];
    const float* W_C    = (const float*)d_in[5];
    const float* D_skip = (const float*)d_in[6];
    float* out = (float*)d_out;

    float* xt  = (float*)d_ws;
    float* yws = xt + (size_t)VOX * CCH;

    k_transpose_in<<<VOX / 64, 256, 0, stream>>>(x, xt);
    k_scan<<<4096, 768, 0, stream>>>(xt, yws, A_log, W_dt, b_dt, W_B, W_C, D_skip, 0, 4096, 0);
    k_scan<<<4096, 768, 0, stream>>>(xt, yws, A_log, W_dt, b_dt, W_B, W_C, D_skip, 1, 64, 1);
    k_scan<<<4096, 768, 0, stream>>>(xt, yws, A_log, W_dt, b_dt, W_B, W_C, D_skip, 2, 1, 1);
    k_transpose_out<<<VOX / 64, 256, 0, stream>>>(yws, out);
}

// Round 12
// 390.156 us; speedup vs baseline: 1.8753x; 1.2947x over previous
//
#include <hip/hip_runtime.h>
#include <math.h>

#define CCH 48
#define NST 16
#define VOX (64*64*64)

__device__ __forceinline__ float softplus_f(float s) {
    return fmaxf(s, 0.f) + log1pf(__expf(-fabsf(s)));
}

template<int CTRL>
__device__ __forceinline__ float dpp_add(float x) {
    int v = __builtin_amdgcn_update_dpp(0, __float_as_int(x), CTRL, 0xF, 0xF, true);
    return x + __int_as_float(v);
}

__global__ __launch_bounds__(256) void k_transpose_in(const float* __restrict__ x,
                                                      float* __restrict__ xt) {
    __shared__ float tile[CCH * 65];
    int v0 = blockIdx.x * 64;
    int t = threadIdx.x;
#pragma unroll
    for (int i = 0; i < 12; ++i) {
        int idx = t + i * 256;
        int c = idx >> 6, v = idx & 63;
        tile[c * 65 + v] = x[c * VOX + v0 + v];
    }
    __syncthreads();
#pragma unroll
    for (int i = 0; i < 12; ++i) {
        int idx = t + i * 256;
        int v = idx / CCH, c = idx - v * CCH;
        xt[(v0 + v) * CCH + c] = tile[c * 65 + v];
    }
}

__global__ __launch_bounds__(256) void k_transpose_out(const float* __restrict__ yws,
                                                       float* __restrict__ out) {
    __shared__ float tile[CCH * 65];
    int v0 = blockIdx.x * 64;
    int t = threadIdx.x;
#pragma unroll
    for (int i = 0; i < 12; ++i) {
        int idx = t + i * 256;
        int v = idx / CCH, c = idx - v * CCH;
        tile[c * 65 + v] = yws[(v0 + v) * CCH + c];
    }
    __syncthreads();
#pragma unroll
    for (int i = 0; i < 12; ++i) {
        int idx = t + i * 256;
        int c = idx >> 6, v = idx & 63;
        out[c * VOX + v0 + v] = tile[c * 65 + v];
    }
}

// LDS layout (float offsets) — unchanged since round 5.
#define OFF_XS    0        // 3072  xs[l*48+c]
#define OFF_WDT   3072     // 2496  wdtT[c*52+k]
#define OFF_WB    5568     // 832   wBT[n*52+k]
#define OFF_WC    6400     // 832   wCT[n*52+k]
#define OFF_DTS   7232     // 3264  dtsT[c*68+l]
#define OFF_UX    10496    // 3264  uxT[c*68+l]
#define OFF_BC    13760    // 1088  BcsT[n*68+l]
#define OFF_CC    14848    // 1088  CcsT[n*68+l]
#define OFF_YS    3072     // 3072  ys[l*48+c]  (aliases weights after projections)
#define SMEM_FLOATS 15936  // 63,744 B -> 2 blocks/CU by LDS

// Ledger (empirical, this kernel):
//  launch_bounds: arg2=6 -> RA cap 40 VGPR (ok if live-set fits; else spill).
//    arg2=4/2 -> cap 64 -> crosses m69 waves/CU halving -> 1 block/CU,
//    Occ 34%, ~1.9x latency (r8/r9). KEEP (768,6); design phases <= ~32 live.
//  Projection: r5 form (dt: 768 thr; B/C: 256 thr) = 147us baseline.
//    2-pass 4x2 tile (r11) = REGRESSION (+37us: conflicts 1.9e7 + 5-wave
//    concentration). Do not re-try without fixing w-read broadcast.
//  Cross-lane: ror {1,2,4,8} full-16 OK (r5). ror {1,2,4} 8-lane WRONG (r10,
//    direction-dependent wrap). xor-involutions (quad_perm 0xB1/0x4E,
//    row_half_mirror 0x141) are direction-free -> safe for 8-lane groups.
__global__ __launch_bounds__(768, 6) void k_scan(
    const float* __restrict__ xt, float* __restrict__ yws,
    const float* __restrict__ A_log, const float* __restrict__ W_dt,
    const float* __restrict__ b_dt, const float* __restrict__ W_B,
    const float* __restrict__ W_C, const float* __restrict__ D_skip,
    int dir, int stride_v, int accumulate)
{
    __shared__ __align__(16) float smem[SMEM_FLOATS];
    float* xs   = smem + OFF_XS;
    float* wdtT = smem + OFF_WDT;
    float* wBT  = smem + OFF_WB;
    float* wCT  = smem + OFF_WC;
    float* dtsT = smem + OFF_DTS;
    float* uxT  = smem + OFF_UX;
    float* BcsT = smem + OFF_BC;
    float* CcsT = smem + OFF_CC;
    float* ys   = smem + OFF_YS;

    int t = threadIdx.x;
    int lid = blockIdx.x;
    int a = lid >> 6, b = lid & 63;
    int vbase;
    if (dir == 0) vbase = lid;                 // step stride 4096 (along D)
    else if (dir == 1) vbase = a * 4096 + b;   // step stride 64   (along H)
    else vbase = a * 4096 + b * 64;            // step stride 1    (along W)

    const float* wdt_g = W_dt + dir * CCH * CCH;
    const float* wB_g  = W_B + dir * CCH * NST;
    const float* wC_g  = W_C + dir * CCH * NST;

    // ---- stage line of x (one float4 per thread) ----
    {
        int q = t % 12, l = t / 12;
        *(float4*)&xs[l * CCH + 4 * q] =
            *(const float4*)&xt[(vbase + l * stride_v) * CCH + 4 * q];
    }
    // ---- stage transposed weights ----
    for (int idx = t; idx < CCH * CCH; idx += 768) {
        int k = idx / CCH, c2 = idx - k * CCH;
        wdtT[c2 * 52 + k] = wdt_g[idx];
    }
    {
        int k = t >> 4, n2 = t & 15;
        wBT[n2 * 52 + k] = wB_g[t];
        wCT[n2 * 52 + k] = wC_g[t];
    }
    __syncthreads();

    // ---- dt projection: thread owns channel c, 4 CONSECUTIVE positions ----
    // (round-5 form, verbatim: 147us baseline)
    {
        int c  = t % CCH;
        int l0 = t / CCH;                      // 0..15, l = 4*l0 + i
        float bc = b_dt[dir * CCH + c];
        const float4* wr  = (const float4*)&wdtT[c * 52];
        const float4* xr0 = (const float4*)&xs[(4 * l0 + 0) * CCH];
        const float4* xr1 = (const float4*)&xs[(4 * l0 + 1) * CCH];
        const float4* xr2 = (const float4*)&xs[(4 * l0 + 2) * CCH];
        const float4* xr3 = (const float4*)&xs[(4 * l0 + 3) * CCH];
        float s0 = bc, s1 = bc, s2 = bc, s3 = bc;
#pragma unroll
        for (int q = 0; q < 12; ++q) {
            float4 wv = wr[q];
            float4 x0 = xr0[q], x1 = xr1[q], x2 = xr2[q], x3 = xr3[q];
            s0 = fmaf(x0.x, wv.x, s0); s0 = fmaf(x0.y, wv.y, s0);
            s0 = fmaf(x0.z, wv.z, s0); s0 = fmaf(x0.w, wv.w, s0);
            s1 = fmaf(x1.x, wv.x, s1); s1 = fmaf(x1.y, wv.y, s1);
            s1 = fmaf(x1.z, wv.z, s1); s1 = fmaf(x1.w, wv.w, s1);
            s2 = fmaf(x2.x, wv.x, s2); s2 = fmaf(x2.y, wv.y, s2);
            s2 = fmaf(x2.z, wv.z, s2); s2 = fmaf(x2.w, wv.w, s2);
            s3 = fmaf(x3.x, wv.x, s3); s3 = fmaf(x3.y, wv.y, s3);
            s3 = fmaf(x3.z, wv.z, s3); s3 = fmaf(x3.w, wv.w, s3);
        }
        float4 dtv, uxv;
        dtv.x = softplus_f(s0); uxv.x = dtv.x * xs[(4 * l0 + 0) * CCH + c];
        dtv.y = softplus_f(s1); uxv.y = dtv.y * xs[(4 * l0 + 1) * CCH + c];
        dtv.z = softplus_f(s2); uxv.z = dtv.z * xs[(4 * l0 + 2) * CCH + c];
        dtv.w = softplus_f(s3); uxv.w = dtv.w * xs[(4 * l0 + 3) * CCH + c];
        *(float4*)&dtsT[c * 68 + 4 * l0] = dtv;
        *(float4*)&uxT[c * 68 + 4 * l0]  = uxv;
    }
    // ---- B and C projections: thread owns (n, l); stride-68 rows ----
    // (round-5 form, verbatim)
    {
        int n = t & 15;
        int lA = t >> 4;
#pragma unroll
        for (int rep = 0; rep < 2; ++rep) {
            int l = (rep == 0) ? lA : (48 + lA);
            if (rep == 0 || t < 256) {
                const float4* xr  = (const float4*)&xs[l * CCH];
                const float4* wbr = (const float4*)&wBT[n * 52];
                const float4* wcr = (const float4*)&wCT[n * 52];
                float sB = 0.f, sC = 0.f;
#pragma unroll
                for (int q = 0; q < 12; ++q) {
                    float4 xv = xr[q];
                    float4 wb = wbr[q];
                    float4 wc = wcr[q];
                    sB = fmaf(xv.x, wb.x, sB); sC = fmaf(xv.x, wc.x, sC);
                    sB = fmaf(xv.y, wb.y, sB); sC = fmaf(xv.y, wc.y, sC);
                    sB = fmaf(xv.z, wb.z, sB); sC = fmaf(xv.z, wc.z, sC);
                    sB = fmaf(xv.w, wb.w, sB); sC = fmaf(xv.w, wc.w, sC);
                }
                BcsT[n * 68 + l] = sB;
                CcsT[n * 68 + l] = sC;
            }
        }
    }
    __syncthreads();

    // ---- sequential scan: 384 threads, TWO states (c,nh) and (c,nh+8) ----
    // dt/ux rows shared between states -> 6 b128 per l4 (vs 8 at 1-state).
    // Bank map: dt/ux row = 4*cc mod 32, B/C rows = 4*nh mod 32 -> disjoint
    // bank quads, 8-lane broadcast, conflict-free.
    // Reduction: 3 xor-involution dpp steps over the 8-lane nh-group
    // (0xB1=xor1, 0x4E=xor2, 0x141=xor7) -> lane nh==0 holds the 8-sum.
    if (t < 384) {
        int cc = t >> 3, nh = t & 7;
        float a0 = -expf(A_log[dir * CCH * NST + cc * NST + nh]);
        float a1 = -expf(A_log[dir * CCH * NST + cc * NST + nh + 8]);
        const float4* dt4 = (const float4*)&dtsT[cc * 68];
        const float4* ux4 = (const float4*)&uxT[cc * 68];
        const float4* B4a = (const float4*)&BcsT[nh * 68];
        const float4* B4b = (const float4*)&BcsT[(nh + 8) * 68];
        const float4* C4a = (const float4*)&CcsT[nh * 68];
        const float4* C4b = (const float4*)&CcsT[(nh + 8) * 68];
        float h0 = 0.f, h1 = 0.f;

#define STEP(COMP, LIDX)                                                    \
        {                                                                   \
            float e0 = __expf(dtv.COMP * a0);                               \
            float e1 = __expf(dtv.COMP * a1);                               \
            h0 = fmaf(e0, h0, uxv.COMP * Bva.COMP);                         \
            h1 = fmaf(e1, h1, uxv.COMP * Bvb.COMP);                         \
            float p = fmaf(h1, Cvb.COMP, h0 * Cva.COMP);                    \
            p = dpp_add<0xB1>(p);                                           \
            p = dpp_add<0x4E>(p);                                           \
            p = dpp_add<0x141>(p);                                          \
            if (nh == 0) ys[(LIDX) * CCH + cc] = p;                         \
        }

#pragma unroll
        for (int l4 = 0; l4 < 16; ++l4) {
            float4 dtv = dt4[l4];
            float4 uxv = ux4[l4];
            float4 Bva = B4a[l4];
            float4 Bvb = B4b[l4];
            float4 Cva = C4a[l4];
            float4 Cvb = C4b[l4];
            STEP(x, l4 * 4 + 0)
            STEP(y, l4 * 4 + 1)
            STEP(z, l4 * 4 + 2)
            STEP(w, l4 * 4 + 3)
        }
#undef STEP
    }
    __syncthreads();

    // ---- add skip term and write/accumulate to yws ----
    {
        int q = t % 12, l = t / 12;
        float4 yv = *(const float4*)&ys[l * CCH + 4 * q];
        float4 xv = *(const float4*)&xs[l * CCH + 4 * q];
        float4 dv = *(const float4*)&D_skip[dir * CCH + 4 * q];
        yv.x = fmaf(dv.x, xv.x, yv.x);
        yv.y = fmaf(dv.y, xv.y, yv.y);
        yv.z = fmaf(dv.z, xv.z, yv.z);
        yv.w = fmaf(dv.w, xv.w, yv.w);
        float* gp = &yws[(vbase + l * stride_v) * CCH + 4 * q];
        if (accumulate) {
            float4 old = *(const float4*)gp;
            yv.x += old.x; yv.y += old.y; yv.z += old.z; yv.w += old.w;
        }
        *(float4*)gp = yv;
    }
}

extern "C" void kernel_launch(void* const* d_in, const int* in_sizes, int n_in,
                              void* d_out, int out_size, void* d_ws, size_t ws_size,
                              hipStream_t stream) {
    const float* x      = (const float*)d_in[0];
    const float* A_log  = (const float*)d_in[1];
    const float* W_dt   = (const float*)d_in[2];
    const float* b_dt   = (const float*)d_in[3];
    const float* W_B    = (const float*)d_in[4];
    const float* W_C    = (const float*)d_in[5];
    const float* D_skip = (const float*)d_in[6];
    float* out = (float*)d_out;

    float* xt  = (float*)d_ws;
    float* yws = xt + (size_t)VOX * CCH;

    k_transpose_in<<<VOX / 64, 256, 0, stream>>>(x, xt);
    k_scan<<<4096, 768, 0, stream>>>(xt, yws, A_log, W_dt, b_dt, W_B, W_C, D_skip, 0, 4096, 0);
    k_scan<<<4096, 768, 0, stream>>>(xt, yws, A_log, W_dt, b_dt, W_B, W_C, D_skip, 1, 64, 1);
    k_scan<<<4096, 768, 0, stream>>>(xt, yws, A_log, W_dt, b_dt, W_B, W_C, D_skip, 2, 1, 1);
    k_transpose_out<<<VOX / 64, 256, 0, stream>>>(yws, out);
}

// Round 15
// 360.772 us; speedup vs baseline: 2.0280x; 1.0814x over previous
//
#include <hip/hip_runtime.h>
#include <math.h>

#define CCH 48
#define NST 16
#define VOX (64*64*64)

typedef __attribute__((ext_vector_type(8))) short bf16x8_t;
typedef __attribute__((ext_vector_type(4))) float f32x4_t;
typedef unsigned short ushort_t;

__device__ __forceinline__ float softplus_f(float s) {
    return fmaxf(s, 0.f) + log1pf(__expf(-fabsf(s)));
}

__device__ __forceinline__ ushort_t f2bf(float f) {
    unsigned u = __float_as_uint(f);
    unsigned r = (u + 0x7FFF + ((u >> 16) & 1)) >> 16;
    return (ushort_t)r;
}

template<int CTRL>
__device__ __forceinline__ float dpp_add(float x) {
    int v = __builtin_amdgcn_update_dpp(0, __float_as_int(x), CTRL, 0xF, 0xF, true);
    return x + __int_as_float(v);
}

__global__ __launch_bounds__(256) void k_transpose_in(const float* __restrict__ x,
                                                      float* __restrict__ xt) {
    __shared__ float tile[CCH * 65];
    int v0 = blockIdx.x * 64;
    int t = threadIdx.x;
#pragma unroll
    for (int i = 0; i < 12; ++i) {
        int idx = t + i * 256;
        int c = idx >> 6, v = idx & 63;
        tile[c * 65 + v] = x[c * VOX + v0 + v];
    }
    __syncthreads();
#pragma unroll
    for (int i = 0; i < 12; ++i) {
        int idx = t + i * 256;
        int v = idx / CCH, c = idx - v * CCH;
        xt[(v0 + v) * CCH + c] = tile[c * 65 + v];
    }
}

__global__ __launch_bounds__(256) void k_transpose_out(const float* __restrict__ yws,
                                                       float* __restrict__ out) {
    __shared__ float tile[CCH * 65];
    int v0 = blockIdx.x * 64;
    int t = threadIdx.x;
#pragma unroll
    for (int i = 0; i < 12; ++i) {
        int idx = t + i * 256;
        int v = idx / CCH, c = idx - v * CCH;
        tile[c * 65 + v] = yws[(v0 + v) * CCH + c];
    }
    __syncthreads();
#pragma unroll
    for (int i = 0; i < 12; ++i) {
        int idx = t + i * 256;
        int c = idx >> 6, v = idx & 63;
        out[c * VOX + v0 + v] = tile[c * 65 + v];
    }
}

// LDS layout (float offsets):
#define OFF_XS    0        // 3072  xs fp32 [l][48]
#define OFF_XB    3072     // 2304  xs bf16 [l][72] (u16; k 48..63 zero pad)
#define OFF_WB16  5376     // 2880  W bf16 [80][72] (rows 0..47 dt^T, 48..63 B^T, 64..79 C^T)
#define OFF_DTS   8256     // 3264  dtsT[c*68+l]
#define OFF_UX    11520    // 3264  uxT[c*68+l]
#define OFF_BC    14784    // 1088  BcsT[n*68+l]
#define OFF_CC    15872    // 1088  CcsT[n*68+l]
#define OFF_YS    3072     // 3072  ys[l*48+c] (aliases XB+WB16 after MFMA phase)
#define SMEM_FLOATS 16960  // 67,840 B -> 2 blocks/CU

// Ledger (empirical, this kernel):
//  launch_bounds: arg2=6 -> RA cap 40 VGPR. arg2=4/2 -> 64 VGPR -> crosses
//    m69 waves/CU halving -> 1 block/CU, 1.9x latency (r8/r9). KEEP (768,6).
//  Projection: r5 VALU form = 8.5K cyc/block; r12 all-VALU total 20.5K cyc
//    -> 140us, VALUBusy 84% (VALU-bound). This round: projections -> MFMA.
//  Cross-lane: xor-involution dpp (0xB1/0x4E/0x141) 8-lane reduce OK (r12).
//    ror {1,2,4} 8-lane WRONG (r10). MFMA D-layout: col=lane&15,
//    row=(lane>>4)*4+reg (m89-verified).
__global__ __launch_bounds__(768, 6) void k_scan(
    const float* __restrict__ xt, float* __restrict__ yws,
    const float* __restrict__ A_log, const float* __restrict__ W_dt,
    const float* __restrict__ b_dt, const float* __restrict__ W_B,
    const float* __restrict__ W_C, const float* __restrict__ D_skip,
    int dir, int stride_v, int accumulate)
{
    __shared__ __align__(16) float smem[SMEM_FLOATS];
    float* xs   = smem + OFF_XS;
    float* dtsT = smem + OFF_DTS;
    float* uxT  = smem + OFF_UX;
    float* BcsT = smem + OFF_BC;
    float* CcsT = smem + OFF_CC;
    float* ys   = smem + OFF_YS;
    ushort_t* xb = (ushort_t*)(smem + OFF_XB);
    ushort_t* wb = (ushort_t*)(smem + OFF_WB16);

    int t = threadIdx.x;
    int lid = blockIdx.x;
    int a = lid >> 6, b = lid & 63;
    int vbase;
    if (dir == 0) vbase = lid;                 // step stride 4096 (along D)
    else if (dir == 1) vbase = a * 4096 + b;   // step stride 64   (along H)
    else vbase = a * 4096 + b * 64;            // step stride 1    (along W)

    const float* wdt_g = W_dt + dir * CCH * CCH;
    const float* wB_g  = W_B + dir * CCH * NST;
    const float* wC_g  = W_C + dir * CCH * NST;

    // ---- stage line of x: fp32 + bf16 copies ----
    {
        int q = t % 12, l = t / 12;
        float4 v = *(const float4*)&xt[(vbase + l * stride_v) * CCH + 4 * q];
        *(float4*)&xs[l * CCH + 4 * q] = v;
        unsigned p0 = (unsigned)f2bf(v.x) | ((unsigned)f2bf(v.y) << 16);
        unsigned p1 = (unsigned)f2bf(v.z) | ((unsigned)f2bf(v.w) << 16);
        unsigned* d = (unsigned*)&xb[l * 72 + 4 * q];
        d[0] = p0; d[1] = p1;
    }
    // ---- stage weights bf16, transposed: wb[row][k], row = output index ----
    for (int idx = t; idx < 3840; idx += 768) {
        float v; int row, k;
        if (idx < 2304)      { k = idx / 48;       row = idx % 48;        v = wdt_g[idx]; }
        else if (idx < 3072) { int j = idx - 2304; k = j >> 4; row = 48 + (j & 15); v = wB_g[j]; }
        else                 { int j = idx - 3072; k = j >> 4; row = 64 + (j & 15); v = wC_g[j]; }
        wb[row * 72 + k] = f2bf(v);
    }
    // ---- zero K-pads (k = 48..63) ----
    for (int i = t; i < 80 * 16; i += 768) wb[(i >> 4) * 72 + 48 + (i & 15)] = 0;
    for (int i = t; i < 64 * 16; i += 768) xb[(i >> 4) * 72 + 48 + (i & 15)] = 0;
    __syncthreads();

    // ---- MFMA projections: O[80][64] = W(80x48) * x^T(48x64), bf16 in fp32 out.
    // 20 tiles (5 m-tiles x 4 n-tiles), 2 mfma each (K=64 incl. zero pad).
    // A: lane holds A[lane&15][ (lane>>4)*8 + i ]; B: B[(lane>>4)*8+i][lane&15];
    // D: col=lane&15, row=(lane>>4)*4+reg (m89).
    {
        int w = t >> 6, lane = t & 63;
        if (w < 10) {
            int r16 = lane & 15, g = lane >> 4;
#pragma unroll
            for (int tt = 0; tt < 2; ++tt) {
                int tile = w * 2 + tt;
                int tm = tile >> 2, tn = tile & 3;
                const ushort_t* ap = &wb[(tm * 16 + r16) * 72 + g * 8];
                const ushort_t* bp = &xb[(tn * 16 + r16) * 72 + g * 8];
                bf16x8_t A0 = *(const bf16x8_t*)ap;
                bf16x8_t A1 = *(const bf16x8_t*)(ap + 32);
                bf16x8_t B0 = *(const bf16x8_t*)bp;
                bf16x8_t B1 = *(const bf16x8_t*)(bp + 32);
                f32x4_t acc = {0.f, 0.f, 0.f, 0.f};
                acc = __builtin_amdgcn_mfma_f32_16x16x32_bf16(A0, B0, acc, 0, 0, 0);
                acc = __builtin_amdgcn_mfma_f32_16x16x32_bf16(A1, B1, acc, 0, 0, 0);
                int col = tn * 16 + r16;
                float* outp;
                if (tm < 3)       outp = &dtsT[(tm * 16 + g * 4) * 68 + col];
                else if (tm == 3) outp = &BcsT[(g * 4) * 68 + col];
                else              outp = &CcsT[(g * 4) * 68 + col];
                outp[0 * 68] = acc[0];
                outp[1 * 68] = acc[1];
                outp[2 * 68] = acc[2];
                outp[3 * 68] = acc[3];
            }
        }
    }
    __syncthreads();

    // ---- pointwise: bias + softplus on dt; ux = dt * x ----
    {
        int c = t % CCH, l0 = t / CCH;   // l0 0..15, owns l = 4*l0..4*l0+3
        float bias = b_dt[dir * CCH + c];
        float4 dv = *(const float4*)&dtsT[c * 68 + 4 * l0];
        float4 dtv, uxv;
        dtv.x = softplus_f(dv.x + bias); uxv.x = dtv.x * xs[(4 * l0 + 0) * CCH + c];
        dtv.y = softplus_f(dv.y + bias); uxv.y = dtv.y * xs[(4 * l0 + 1) * CCH + c];
        dtv.z = softplus_f(dv.z + bias); uxv.z = dtv.z * xs[(4 * l0 + 2) * CCH + c];
        dtv.w = softplus_f(dv.w + bias); uxv.w = dtv.w * xs[(4 * l0 + 3) * CCH + c];
        *(float4*)&dtsT[c * 68 + 4 * l0] = dtv;
        *(float4*)&uxT[c * 68 + 4 * l0]  = uxv;
    }
    __syncthreads();

    // ---- sequential scan: 384 threads, TWO states (c,nh) and (c,nh+8) ----
    // (r12 verbatim: xor-involution dpp reduce, conflict-free bank map)
    if (t < 384) {
        int cc = t >> 3, nh = t & 7;
        float a0 = -expf(A_log[dir * CCH * NST + cc * NST + nh]);
        float a1 = -expf(A_log[dir * CCH * NST + cc * NST + nh + 8]);
        const float4* dt4 = (const float4*)&dtsT[cc * 68];
        const float4* ux4 = (const float4*)&uxT[cc * 68];
        const float4* B4a = (const float4*)&BcsT[nh * 68];
        const float4* B4b = (const float4*)&BcsT[(nh + 8) * 68];
        const float4* C4a = (const float4*)&CcsT[nh * 68];
        const float4* C4b = (const float4*)&CcsT[(nh + 8) * 68];
        float h0 = 0.f, h1 = 0.f;

#define STEP(COMP, LIDX)                                                    \
        {                                                                   \
            float e0 = __expf(dtv.COMP * a0);                               \
            float e1 = __expf(dtv.COMP * a1);                               \
            h0 = fmaf(e0, h0, uxv.COMP * Bva.COMP);                         \
            h1 = fmaf(e1, h1, uxv.COMP * Bvb.COMP);                         \
            float p = fmaf(h1, Cvb.COMP, h0 * Cva.COMP);                    \
            p = dpp_add<0xB1>(p);                                           \
            p = dpp_add<0x4E>(p);                                           \
            p = dpp_add<0x141>(p);                                          \
            if (nh == 0) ys[(LIDX) * CCH + cc] = p;                         \
        }

#pragma unroll
        for (int l4 = 0; l4 < 16; ++l4) {
            float4 dtv = dt4[l4];
            float4 uxv = ux4[l4];
            float4 Bva = B4a[l4];
            float4 Bvb = B4b[l4];
            float4 Cva = C4a[l4];
            float4 Cvb = C4b[l4];
            STEP(x, l4 * 4 + 0)
            STEP(y, l4 * 4 + 1)
            STEP(z, l4 * 4 + 2)
            STEP(w, l4 * 4 + 3)
        }
#undef STEP
    }
    __syncthreads();

    // ---- add skip term and write/accumulate to yws ----
    {
        int q = t % 12, l = t / 12;
        float4 yv = *(const float4*)&ys[l * CCH + 4 * q];
        float4 xv = *(const float4*)&xs[l * CCH + 4 * q];
        float4 dv = *(const float4*)&D_skip[dir * CCH + 4 * q];
        yv.x = fmaf(dv.x, xv.x, yv.x);
        yv.y = fmaf(dv.y, xv.y, yv.y);
        yv.z = fmaf(dv.z, xv.z, yv.z);
        yv.w = fmaf(dv.w, xv.w, yv.w);
        float* gp = &yws[(vbase + l * stride_v) * CCH + 4 * q];
        if (accumulate) {
            float4 old = *(const float4*)gp;
            yv.x += old.x; yv.y += old.y; yv.z += old.z; yv.w += old.w;
        }
        *(float4*)gp = yv;
    }
}

extern "C" void kernel_launch(void* const* d_in, const int* in_sizes, int n_in,
                              void* d_out, int out_size, void* d_ws, size_t ws_size,
                              hipStream_t stream) {
    const float* x      = (const float*)d_in[0];
    const float* A_log  = (const float*)d_in[1];
    const float* W_dt   = (const float*)d_in[2];
    const float* b_dt   = (const float*)d_in[3];
    const float* W_B    = (const float*)d_in[4];
    const float* W_C    = (const float*)d_in[5];
    const float* D_skip = (const float*)d_in[6];
    float* out = (float*)d_out;

    float* xt  = (float*)d_ws;
    float* yws = xt + (size_t)VOX * CCH;

    k_transpose_in<<<VOX / 64, 256, 0, stream>>>(x, xt);
    k_scan<<<4096, 768, 0, stream>>>(xt, yws, A_log, W_dt, b_dt, W_B, W_C, D_skip, 0, 4096, 0);
    k_scan<<<4096, 768, 0, stream>>>(xt, yws, A_log, W_dt, b_dt, W_B, W_C, D_skip, 1, 64, 1);
    k_scan<<<4096, 768, 0, stream>>>(xt, yws, A_log, W_dt, b_dt, W_B, W_C, D_skip, 2, 1, 1);
    k_transpose_out<<<VOX / 64, 256, 0, stream>>>(yws, out);
}